// Round 1
// baseline (321.471 us; speedup 1.0000x reference)
//
#include <hip/hip_runtime.h>
#include <hip/hip_bf16.h>

typedef __attribute__((ext_vector_type(8))) short short8;   // 8 bf16 (4 VGPRs)
typedef __attribute__((ext_vector_type(4))) short short4v;  // 4 bf16 (8B)
typedef __attribute__((ext_vector_type(4))) float f32x4;

#define MFMA16(a,b,c) __builtin_amdgcn_mfma_f32_16x16x32_bf16(a,b,c,0,0,0)

__device__ __forceinline__ unsigned short f2b_rne(float f){
  union { float f; unsigned int u; } v; v.f = f;
  unsigned int u = v.u;
  return (unsigned short)((u + 0x7FFFu + ((u >> 16) & 1u)) >> 16);
}

// ---------------- convert fp32 -> bf16, 8 elems/thread ----------------
__global__ __launch_bounds__(256) void k_cvt(const float* __restrict__ in,
                                             unsigned short* __restrict__ out, int n8){
  int i = blockIdx.x * 256 + threadIdx.x;
  if (i >= n8) return;
  const float4* p = (const float4*)in + (size_t)i * 2;
  float4 a = p[0], b = p[1];
  short8 o;
  o[0] = (short)f2b_rne(a.x); o[1] = (short)f2b_rne(a.y);
  o[2] = (short)f2b_rne(a.z); o[3] = (short)f2b_rne(a.w);
  o[4] = (short)f2b_rne(b.x); o[5] = (short)f2b_rne(b.y);
  o[6] = (short)f2b_rne(b.z); o[7] = (short)f2b_rne(b.w);
  *((short8*)out + i) = o;
}

// ---------------- transpose + convert: in[R][Cc] f32 -> out[Cc][R] bf16 ----------------
__global__ void k_transpose_cvt(const float* __restrict__ in, unsigned short* __restrict__ out,
                                int R, int Cc){
  __shared__ unsigned short tile[32][33];
  int c0 = blockIdx.x * 32, r0 = blockIdx.y * 32;
  int tx = threadIdx.x, ty = threadIdx.y;   // block (32,8)
  #pragma unroll
  for (int i = 0; i < 32; i += 8)
    tile[ty + i][tx] = f2b_rne(in[(size_t)(r0 + ty + i) * Cc + c0 + tx]);
  __syncthreads();
  #pragma unroll
  for (int i = 0; i < 32; i += 8)
    out[(size_t)(c0 + ty + i) * R + r0 + tx] = tile[tx][ty + i];
}

// ---------------- QKV GEMM: xb[8192][768] @ wqkvt[2304][768]^T, scatter q/k/vt ----------------
__global__ __launch_bounds__(256) void k_gemm_qkv(
    const unsigned short* __restrict__ A,     // xb
    const unsigned short* __restrict__ Bt,    // wqkvt [j][c]
    unsigned short* __restrict__ qbuf,        // [B*H][4096][96], pre-scaled
    unsigned short* __restrict__ kbuf,        // [B*H][4096][96]
    unsigned short* __restrict__ vtb)         // [B*H][96][4096]
{
  __shared__ short As[128 * 40];   // rows padded 32->40 elems (80B stride)
  __shared__ short Bs[128 * 40];
  int m0 = blockIdx.x * 128, n0 = blockIdx.y * 128;
  int t = threadIdx.x, l = t & 63, w = t >> 6;
  int lr = l & 15, lh = l >> 4;
  int wr = w >> 1, wc = w & 1;

  int row0 = t >> 2, cs0 = t & 3;
  int row1 = row0 + 64;
  const unsigned short* ga0 = A  + (size_t)(m0 + row0) * 768 + cs0 * 8;
  const unsigned short* ga1 = A  + (size_t)(m0 + row1) * 768 + cs0 * 8;
  const unsigned short* gb0 = Bt + (size_t)(n0 + row0) * 768 + cs0 * 8;
  const unsigned short* gb1 = Bt + (size_t)(n0 + row1) * 768 + cs0 * 8;
  short* la0 = As + row0 * 40 + cs0 * 8;
  short* la1 = As + row1 * 40 + cs0 * 8;
  short* lb0 = Bs + row0 * 40 + cs0 * 8;
  short* lb1 = Bs + row1 * 40 + cs0 * 8;

  f32x4 acc[4][4];
  f32x4 z4 = {0.f, 0.f, 0.f, 0.f};
  #pragma unroll
  for (int mf = 0; mf < 4; ++mf)
    #pragma unroll
    for (int nf = 0; nf < 4; ++nf) acc[mf][nf] = z4;

  short8 ra0 = *(const short8*)ga0;
  short8 ra1 = *(const short8*)ga1;
  short8 rb0 = *(const short8*)gb0;
  short8 rb1 = *(const short8*)gb1;

  for (int kt = 0; kt < 24; ++kt){
    __syncthreads();
    *(short8*)la0 = ra0; *(short8*)la1 = ra1;
    *(short8*)lb0 = rb0; *(short8*)lb1 = rb1;
    __syncthreads();
    if (kt < 23){
      ra0 = *(const short8*)(ga0 + (kt + 1) * 32);
      ra1 = *(const short8*)(ga1 + (kt + 1) * 32);
      rb0 = *(const short8*)(gb0 + (kt + 1) * 32);
      rb1 = *(const short8*)(gb1 + (kt + 1) * 32);
    }
    short8 af[4], bfm[4];
    #pragma unroll
    for (int mf = 0; mf < 4; ++mf)
      af[mf] = *(const short8*)(As + (wr * 64 + mf * 16 + lr) * 40 + lh * 8);
    #pragma unroll
    for (int nf = 0; nf < 4; ++nf)
      bfm[nf] = *(const short8*)(Bs + (wc * 64 + nf * 16 + lr) * 40 + lh * 8);
    #pragma unroll
    for (int mf = 0; mf < 4; ++mf)
      #pragma unroll
      for (int nf = 0; nf < 4; ++nf)
        acc[mf][nf] = MFMA16(af[mf], bfm[nf], acc[mf][nf]);
  }

  const float qscale = 0.10206207261596577f;  // 96^-0.5, folded into Q
  int three = n0 / 768;            // uniform per block (768 % 128 == 0)
  int b_ = m0 >> 12;               // block rows stay within one batch
  int ntok0 = m0 & 4095;
  #pragma unroll
  for (int nf = 0; nf < 4; ++nf){
    int gcol = n0 + wc * 64 + nf * 16 + lr;
    int jj = gcol - three * 768;
    int h = jj / 96;
    int dh = jj - h * 96;
    #pragma unroll
    for (int mf = 0; mf < 4; ++mf){
      int ntok = ntok0 + wr * 64 + mf * 16 + lh * 4;
      if (three == 0){
        unsigned short* dst = qbuf + (size_t)(b_ * 8 + h) * 4096 * 96;
        #pragma unroll
        for (int r = 0; r < 4; ++r)
          dst[(size_t)(ntok + r) * 96 + dh] = f2b_rne(acc[mf][nf][r] * qscale);
      } else if (three == 1){
        unsigned short* dst = kbuf + (size_t)(b_ * 8 + h) * 4096 * 96;
        #pragma unroll
        for (int r = 0; r < 4; ++r)
          dst[(size_t)(ntok + r) * 96 + dh] = f2b_rne(acc[mf][nf][r]);
      } else {
        short4v sv;
        #pragma unroll
        for (int r = 0; r < 4; ++r) sv[r] = (short)f2b_rne(acc[mf][nf][r]);
        *(short4v*)(vtb + ((size_t)(b_ * 8 + h) * 96 + dh) * 4096 + ntok) = sv;
      }
    }
  }
}

// ---------------- flash attention ----------------
// grid (64 qtiles, 16 bh), 256 threads. QBLK=64 (16 q-rows/wave), KVBLK=128.
__global__ __launch_bounds__(256) void k_attn(
    const unsigned short* __restrict__ qb,
    const unsigned short* __restrict__ kb,
    const unsigned short* __restrict__ vtb,
    unsigned short* __restrict__ ao)      // [B*4096][768] bf16
{
  __shared__ short Ks[128 * 120];   // K rows padded 96->120 (240B stride, 2-way free)
  __shared__ short Vs[96 * 136];    // VT rows padded 128->136 (272B stride)
  __shared__ short Ps[4 * 16 * 136];
  int qt = blockIdx.x, bh = blockIdx.y;
  int t = threadIdx.x, l = t & 63, w = t >> 6;
  int lr = l & 15, lh = l >> 4;
  int q0 = qt * 64;
  const unsigned short* qbase = qb  + (size_t)bh * 4096 * 96;
  const unsigned short* kbase = kb  + (size_t)bh * 4096 * 96;
  const unsigned short* vbase = vtb + (size_t)bh * 96 * 4096;

  // Q fragments hoisted to registers (scale already folded in)
  short8 qf[3];
  #pragma unroll
  for (int kf = 0; kf < 3; ++kf)
    qf[kf] = *(const short8*)(qbase + (size_t)(q0 + w * 16 + lr) * 96 + kf * 32 + lh * 8);

  f32x4 oacc[6];
  f32x4 z4 = {0.f, 0.f, 0.f, 0.f};
  #pragma unroll
  for (int df = 0; df < 6; ++df) oacc[df] = z4;
  float mrun[4], lrun[4];
  #pragma unroll
  for (int r = 0; r < 4; ++r){ mrun[r] = -3.0e38f; lrun[r] = 0.f; }

  // staging index precompute (6 × 16B segs per thread per array)
  int vr[6], vc[6];
  short *kl[6], *vl[6];
  #pragma unroll
  for (int i = 0; i < 6; ++i){
    int s = t + i * 256;
    int kr = s / 12, kc = s - kr * 12;
    kl[i] = Ks + kr * 120 + kc * 8;
    vr[i] = s >> 4; vc[i] = s & 15;
    vl[i] = Vs + vr[i] * 136 + vc[i] * 8;
  }

  short8 rk[6], rv[6];
  #pragma unroll
  for (int i = 0; i < 6; ++i){
    rk[i] = *(const short8*)(kbase + (size_t)(t + i * 256) * 8);
    rv[i] = *(const short8*)(vbase + (size_t)vr[i] * 4096 + vc[i] * 8);
  }

  short* Pw = Ps + w * (16 * 136);

  for (int kt = 0; kt < 32; ++kt){
    __syncthreads();
    #pragma unroll
    for (int i = 0; i < 6; ++i){
      *(short8*)kl[i] = rk[i];
      *(short8*)vl[i] = rv[i];
    }
    __syncthreads();
    if (kt < 31){
      #pragma unroll
      for (int i = 0; i < 6; ++i){
        rk[i] = *(const short8*)(kbase + (size_t)(kt + 1) * 12288 + (size_t)(t + i * 256) * 8);
        rv[i] = *(const short8*)(vbase + (size_t)vr[i] * 4096 + (kt + 1) * 128 + vc[i] * 8);
      }
    }
    // S = Q K^T : 16q x 128k per wave
    f32x4 so[8];
    #pragma unroll
    for (int nf = 0; nf < 8; ++nf) so[nf] = z4;
    #pragma unroll
    for (int nf = 0; nf < 8; ++nf){
      const short* kr0 = Ks + (nf * 16 + lr) * 120 + lh * 8;
      short8 b0 = *(const short8*)(kr0);
      short8 b1 = *(const short8*)(kr0 + 32);
      short8 b2 = *(const short8*)(kr0 + 64);
      so[nf] = MFMA16(qf[0], b0, so[nf]);
      so[nf] = MFMA16(qf[1], b1, so[nf]);
      so[nf] = MFMA16(qf[2], b2, so[nf]);
    }
    // online softmax; lane holds S[q=lh*4+r][k=nf*16+lr]
    float alpha[4];
    #pragma unroll
    for (int r = 0; r < 4; ++r){
      float mx = so[0][r];
      #pragma unroll
      for (int nf = 1; nf < 8; ++nf) mx = fmaxf(mx, so[nf][r]);
      #pragma unroll
      for (int mm = 1; mm < 16; mm <<= 1) mx = fmaxf(mx, __shfl_xor(mx, mm, 64));
      float mn = fmaxf(mrun[r], mx);
      alpha[r] = __expf(mrun[r] - mn);
      mrun[r] = mn;
      float sum = 0.f;
      short* pw = Pw + (lh * 4 + r) * 136 + lr;
      #pragma unroll
      for (int nf = 0; nf < 8; ++nf){
        float p = __expf(so[nf][r] - mn);
        sum += p;
        pw[nf * 16] = (short)f2b_rne(p);
      }
      #pragma unroll
      for (int mm = 1; mm < 16; mm <<= 1) sum += __shfl_xor(sum, mm, 64);
      lrun[r] = lrun[r] * alpha[r] + sum;
    }
    #pragma unroll
    for (int df = 0; df < 6; ++df)
      #pragma unroll
      for (int r = 0; r < 4; ++r) oacc[df][r] *= alpha[r];
    asm volatile("s_waitcnt lgkmcnt(0)" ::: "memory");  // P writes visible wave-wide
    // PV: O += P @ V
    #pragma unroll
    for (int kf = 0; kf < 4; ++kf){
      short8 pf = *(const short8*)(Pw + lr * 136 + kf * 32 + lh * 8);
      #pragma unroll
      for (int df = 0; df < 6; ++df){
        short8 vf = *(const short8*)(Vs + (df * 16 + lr) * 136 + kf * 32 + lh * 8);
        oacc[df] = MFMA16(pf, vf, oacc[df]);
      }
    }
  }
  // epilogue: normalize, write bf16 attn output in [B][N][C] layout
  int b = bh >> 3, h = bh & 7;
  #pragma unroll
  for (int df = 0; df < 6; ++df){
    #pragma unroll
    for (int r = 0; r < 4; ++r){
      float val = oacc[df][r] / lrun[r];
      ao[(size_t)(b * 4096 + q0 + w * 16 + lh * 4 + r) * 768 + h * 96 + df * 16 + lr] = f2b_rne(val);
    }
  }
}

// ---------------- proj GEMM: ao[8192][768] @ wprojt[768][768]^T + bias -> f32 out ----------------
__global__ __launch_bounds__(256) void k_gemm_proj(
    const unsigned short* __restrict__ A,
    const unsigned short* __restrict__ Bt,
    const float* __restrict__ bias,
    float* __restrict__ out)
{
  __shared__ short As[128 * 40];
  __shared__ short Bs[128 * 40];
  int m0 = blockIdx.x * 128, n0 = blockIdx.y * 128;
  int t = threadIdx.x, l = t & 63, w = t >> 6;
  int lr = l & 15, lh = l >> 4;
  int wr = w >> 1, wc = w & 1;

  int row0 = t >> 2, cs0 = t & 3;
  int row1 = row0 + 64;
  const unsigned short* ga0 = A  + (size_t)(m0 + row0) * 768 + cs0 * 8;
  const unsigned short* ga1 = A  + (size_t)(m0 + row1) * 768 + cs0 * 8;
  const unsigned short* gb0 = Bt + (size_t)(n0 + row0) * 768 + cs0 * 8;
  const unsigned short* gb1 = Bt + (size_t)(n0 + row1) * 768 + cs0 * 8;
  short* la0 = As + row0 * 40 + cs0 * 8;
  short* la1 = As + row1 * 40 + cs0 * 8;
  short* lb0 = Bs + row0 * 40 + cs0 * 8;
  short* lb1 = Bs + row1 * 40 + cs0 * 8;

  f32x4 acc[4][4];
  f32x4 z4 = {0.f, 0.f, 0.f, 0.f};
  #pragma unroll
  for (int mf = 0; mf < 4; ++mf)
    #pragma unroll
    for (int nf = 0; nf < 4; ++nf) acc[mf][nf] = z4;

  short8 ra0 = *(const short8*)ga0;
  short8 ra1 = *(const short8*)ga1;
  short8 rb0 = *(const short8*)gb0;
  short8 rb1 = *(const short8*)gb1;

  for (int kt = 0; kt < 24; ++kt){
    __syncthreads();
    *(short8*)la0 = ra0; *(short8*)la1 = ra1;
    *(short8*)lb0 = rb0; *(short8*)lb1 = rb1;
    __syncthreads();
    if (kt < 23){
      ra0 = *(const short8*)(ga0 + (kt + 1) * 32);
      ra1 = *(const short8*)(ga1 + (kt + 1) * 32);
      rb0 = *(const short8*)(gb0 + (kt + 1) * 32);
      rb1 = *(const short8*)(gb1 + (kt + 1) * 32);
    }
    short8 af[4], bfm[4];
    #pragma unroll
    for (int mf = 0; mf < 4; ++mf)
      af[mf] = *(const short8*)(As + (wr * 64 + mf * 16 + lr) * 40 + lh * 8);
    #pragma unroll
    for (int nf = 0; nf < 4; ++nf)
      bfm[nf] = *(const short8*)(Bs + (wc * 64 + nf * 16 + lr) * 40 + lh * 8);
    #pragma unroll
    for (int mf = 0; mf < 4; ++mf)
      #pragma unroll
      for (int nf = 0; nf < 4; ++nf)
        acc[mf][nf] = MFMA16(af[mf], bfm[nf], acc[mf][nf]);
  }

  #pragma unroll
  for (int nf = 0; nf < 4; ++nf){
    int gcol = n0 + wc * 64 + nf * 16 + lr;
    float bb = bias[gcol];
    #pragma unroll
    for (int mf = 0; mf < 4; ++mf){
      int grow = m0 + wr * 64 + mf * 16 + lh * 4;
      #pragma unroll
      for (int r = 0; r < 4; ++r)
        out[(size_t)(grow + r) * 768 + gcol] = acc[mf][nf][r] + bb;
    }
  }
}

extern "C" void kernel_launch(void* const* d_in, const int* in_sizes, int n_in,
                              void* d_out, int out_size, void* d_ws, size_t ws_size,
                              hipStream_t stream) {
  const float* x      = (const float*)d_in[0];
  const float* w_qkv  = (const float*)d_in[1];
  const float* w_proj = (const float*)d_in[2];
  const float* b_proj = (const float*)d_in[3];
  float* out = (float*)d_out;
  char* ws = (char*)d_ws;

  // workspace layout (all 16B-aligned); ao aliases xb (xb dead after qkv gemm)
  unsigned short* xb     = (unsigned short*)(ws);                 // 12,582,912 B
  unsigned short* wqkvt  = (unsigned short*)(ws + 12582912);      //  3,538,944 B
  unsigned short* wprojt = (unsigned short*)(ws + 16121856);      //  1,179,648 B
  unsigned short* qbuf   = (unsigned short*)(ws + 17301504);      // 12,582,912 B
  unsigned short* kbuf   = (unsigned short*)(ws + 29884416);      // 12,582,912 B
  unsigned short* vtb    = (unsigned short*)(ws + 42467328);      // 12,582,912 B
  unsigned short* aob    = xb;                                    // reuse

  k_cvt<<<3072, 256, 0, stream>>>(x, xb, 786432);                       // 2*4096*768 / 8
  k_transpose_cvt<<<dim3(72, 24), dim3(32, 8), 0, stream>>>(w_qkv, wqkvt, 768, 2304);
  k_transpose_cvt<<<dim3(24, 24), dim3(32, 8), 0, stream>>>(w_proj, wprojt, 768, 768);
  k_gemm_qkv<<<dim3(64, 18), 256, 0, stream>>>(xb, wqkvt, qbuf, kbuf, vtb);
  k_attn<<<dim3(64, 16), 256, 0, stream>>>(qbuf, kbuf, vtb, aob);
  k_gemm_proj<<<dim3(64, 6), 256, 0, stream>>>(aob, wprojt, b_proj, out);
}

// Round 2
// 229.529 us; speedup vs baseline: 1.4006x; 1.4006x over previous
//
#include <hip/hip_runtime.h>
#include <hip/hip_bf16.h>

typedef __attribute__((ext_vector_type(8))) short short8;   // 8 bf16 (4 VGPRs)
typedef __attribute__((ext_vector_type(4))) short short4v;  // 4 bf16 (8B)
typedef __attribute__((ext_vector_type(4))) float f32x4;
typedef __attribute__((ext_vector_type(16))) float f32x16;

#define MFMA16(a,b,c) __builtin_amdgcn_mfma_f32_16x16x32_bf16(a,b,c,0,0,0)
#define MFMA32(a,b,c) __builtin_amdgcn_mfma_f32_32x32x16_bf16(a,b,c,0,0,0)

__device__ __forceinline__ unsigned short f2b_rne(float f){
  union { float f; unsigned int u; } v; v.f = f;
  unsigned int u = v.u;
  return (unsigned short)((u + 0x7FFFu + ((u >> 16) & 1u)) >> 16);
}

__device__ __forceinline__ f32x16 zero16(){
  f32x16 z;
  #pragma unroll
  for (int i = 0; i < 16; ++i) z[i] = 0.f;
  return z;
}

// ---------------- convert fp32 -> bf16, 8 elems/thread ----------------
__global__ __launch_bounds__(256) void k_cvt(const float* __restrict__ in,
                                             unsigned short* __restrict__ out, int n8){
  int i = blockIdx.x * 256 + threadIdx.x;
  if (i >= n8) return;
  const float4* p = (const float4*)in + (size_t)i * 2;
  float4 a = p[0], b = p[1];
  short8 o;
  o[0] = (short)f2b_rne(a.x); o[1] = (short)f2b_rne(a.y);
  o[2] = (short)f2b_rne(a.z); o[3] = (short)f2b_rne(a.w);
  o[4] = (short)f2b_rne(b.x); o[5] = (short)f2b_rne(b.y);
  o[6] = (short)f2b_rne(b.z); o[7] = (short)f2b_rne(b.w);
  *((short8*)out + i) = o;
}

// ---------------- transpose + convert: in[R][Cc] f32 -> out[Cc][R] bf16 ----------------
__global__ void k_transpose_cvt(const float* __restrict__ in, unsigned short* __restrict__ out,
                                int R, int Cc){
  __shared__ unsigned short tile[32][33];
  int c0 = blockIdx.x * 32, r0 = blockIdx.y * 32;
  int tx = threadIdx.x, ty = threadIdx.y;   // block (32,8)
  #pragma unroll
  for (int i = 0; i < 32; i += 8)
    tile[ty + i][tx] = f2b_rne(in[(size_t)(r0 + ty + i) * Cc + c0 + tx]);
  __syncthreads();
  #pragma unroll
  for (int i = 0; i < 32; i += 8)
    out[(size_t)(c0 + ty + i) * R + r0 + tx] = tile[tx][ty + i];
}

// ---------------- QKV GEMM: xb[8192][768] @ wqkvt[2304][768]^T, scatter q/k/vt ----------------
__global__ __launch_bounds__(256) void k_gemm_qkv(
    const unsigned short* __restrict__ A,     // xb
    const unsigned short* __restrict__ Bt,    // wqkvt [j][c]
    unsigned short* __restrict__ qbuf,        // [B*H][4096][96], pre-scaled (Dh^-0.5 * log2e)
    unsigned short* __restrict__ kbuf,        // [B*H][4096][96]
    unsigned short* __restrict__ vtb)         // [B*H][96][4096]
{
  __shared__ short As[128 * 40];   // rows padded 32->40 elems (80B stride)
  __shared__ short Bs[128 * 40];
  int m0 = blockIdx.x * 128, n0 = blockIdx.y * 128;
  int t = threadIdx.x, l = t & 63, w = t >> 6;
  int lr = l & 15, lh = l >> 4;
  int wr = w >> 1, wc = w & 1;

  int row0 = t >> 2, cs0 = t & 3;
  int row1 = row0 + 64;
  const unsigned short* ga0 = A  + (size_t)(m0 + row0) * 768 + cs0 * 8;
  const unsigned short* ga1 = A  + (size_t)(m0 + row1) * 768 + cs0 * 8;
  const unsigned short* gb0 = Bt + (size_t)(n0 + row0) * 768 + cs0 * 8;
  const unsigned short* gb1 = Bt + (size_t)(n0 + row1) * 768 + cs0 * 8;
  short* la0 = As + row0 * 40 + cs0 * 8;
  short* la1 = As + row1 * 40 + cs0 * 8;
  short* lb0 = Bs + row0 * 40 + cs0 * 8;
  short* lb1 = Bs + row1 * 40 + cs0 * 8;

  f32x4 acc[4][4];
  f32x4 z4 = {0.f, 0.f, 0.f, 0.f};
  #pragma unroll
  for (int mf = 0; mf < 4; ++mf)
    #pragma unroll
    for (int nf = 0; nf < 4; ++nf) acc[mf][nf] = z4;

  short8 ra0 = *(const short8*)ga0;
  short8 ra1 = *(const short8*)ga1;
  short8 rb0 = *(const short8*)gb0;
  short8 rb1 = *(const short8*)gb1;

  for (int kt = 0; kt < 24; ++kt){
    __syncthreads();
    *(short8*)la0 = ra0; *(short8*)la1 = ra1;
    *(short8*)lb0 = rb0; *(short8*)lb1 = rb1;
    __syncthreads();
    if (kt < 23){
      ra0 = *(const short8*)(ga0 + (kt + 1) * 32);
      ra1 = *(const short8*)(ga1 + (kt + 1) * 32);
      rb0 = *(const short8*)(gb0 + (kt + 1) * 32);
      rb1 = *(const short8*)(gb1 + (kt + 1) * 32);
    }
    short8 af[4], bfm[4];
    #pragma unroll
    for (int mf = 0; mf < 4; ++mf)
      af[mf] = *(const short8*)(As + (wr * 64 + mf * 16 + lr) * 40 + lh * 8);
    #pragma unroll
    for (int nf = 0; nf < 4; ++nf)
      bfm[nf] = *(const short8*)(Bs + (wc * 64 + nf * 16 + lr) * 40 + lh * 8);
    #pragma unroll
    for (int mf = 0; mf < 4; ++mf)
      #pragma unroll
      for (int nf = 0; nf < 4; ++nf)
        acc[mf][nf] = MFMA16(af[mf], bfm[nf], acc[mf][nf]);
  }

  // Dh^-0.5 * log2(e) folded into Q so attention can use exp2
  const float qscale = 0.10206207261596577f * 1.4426950408889634f;
  int three = n0 / 768;            // uniform per block (768 % 128 == 0)
  int b_ = m0 >> 12;               // block rows stay within one batch
  int ntok0 = m0 & 4095;
  #pragma unroll
  for (int nf = 0; nf < 4; ++nf){
    int gcol = n0 + wc * 64 + nf * 16 + lr;
    int jj = gcol - three * 768;
    int h = jj / 96;
    int dh = jj - h * 96;
    #pragma unroll
    for (int mf = 0; mf < 4; ++mf){
      int ntok = ntok0 + wr * 64 + mf * 16 + lh * 4;
      if (three == 0){
        unsigned short* dst = qbuf + (size_t)(b_ * 8 + h) * 4096 * 96;
        #pragma unroll
        for (int r = 0; r < 4; ++r)
          dst[(size_t)(ntok + r) * 96 + dh] = f2b_rne(acc[mf][nf][r] * qscale);
      } else if (three == 1){
        unsigned short* dst = kbuf + (size_t)(b_ * 8 + h) * 4096 * 96;
        #pragma unroll
        for (int r = 0; r < 4; ++r)
          dst[(size_t)(ntok + r) * 96 + dh] = f2b_rne(acc[mf][nf][r]);
      } else {
        short4v sv;
        #pragma unroll
        for (int r = 0; r < 4; ++r) sv[r] = (short)f2b_rne(acc[mf][nf][r]);
        *(short4v*)(vtb + ((size_t)(b_ * 8 + h) * 96 + dh) * 4096 + ntok) = sv;
      }
    }
  }
}

// ---------------- flash attention v2: swapped QK^T, in-register softmax ----------------
// grid (16 bh, 16 qtiles), 512 threads = 8 warps x 32 q-rows. KVBLK=64.
// S^T = mfma32(A=K, B=Q): lane ln owns q-column q0+ (ln&31); regs hold k.
// PV: O^T = mfma32(A=V^T, B=P^T) with P^T built in-register via cvt_pk + permlane32_swap.
__global__ __launch_bounds__(512) void k_attn2(
    const unsigned short* __restrict__ qb,
    const unsigned short* __restrict__ kb,
    const unsigned short* __restrict__ vtb,
    unsigned short* __restrict__ ao)      // [B*4096][768] bf16
{
  // LDS (shorts): Ks buf b at b*6656, 64 rows x stride 104 (208B: 16B-granule stride 13 -> 8 quads)
  //               Vs buf b at 13312 + b*6912, 96 rows x stride 72 (144B: granule stride 9)
  __shared__ short lds[27136];    // 54272 B
  const int bh = blockIdx.x;      // x = bh -> same-bh blocks share an XCD (L2 locality)
  const int qt = blockIdx.y;
  const int tid = threadIdx.x;
  const int ln = tid & 63, wid = tid >> 6;
  const int qc = ln & 31, hi = ln >> 5;
  const int q0 = qt * 256 + wid * 32;

  const unsigned short* qbase = qb  + (size_t)bh * 4096 * 96;
  const unsigned short* kbase = kb  + (size_t)bh * 4096 * 96;
  const unsigned short* vbase = vtb + (size_t)bh * 96 * 4096;

  // Q B-fragments hoisted: lane holds Q[q0+qc][kw*16 + hi*8 + e]
  short8 qf[6];
  #pragma unroll
  for (int kw = 0; kw < 6; ++kw)
    qf[kw] = *(const short8*)(qbase + (size_t)(q0 + qc) * 96 + kw * 16 + hi * 8);

  // staging: 1536 x 16B chunks (K: 768, V^T: 768); 3 per thread
  const unsigned short* gp[3]; int gstep[3], loff[3], lstep[3];
  #pragma unroll
  for (int j = 0; j < 3; ++j){
    int c = tid + j * 512;
    if (c < 768){
      int r = c / 12, cl = c - r * 12;
      gp[j] = kbase + r * 96 + cl * 8; gstep[j] = 64 * 96;
      loff[j] = r * 104 + cl * 8;      lstep[j] = 6656;
    } else {
      int cv = c - 768; int r = cv >> 3, cl = cv & 7;
      gp[j] = vbase + (size_t)r * 4096 + cl * 8; gstep[j] = 64;
      loff[j] = 13312 + r * 72 + cl * 8;         lstep[j] = 6912;
    }
  }

  short8 rs[3];
  #pragma unroll
  for (int j = 0; j < 3; ++j){ rs[j] = *(const short8*)gp[j]; gp[j] += gstep[j]; }
  #pragma unroll
  for (int j = 0; j < 3; ++j) *(short8*)(lds + loff[j]) = rs[j];   // buf 0

  f32x16 oacc[3];
  #pragma unroll
  for (int dt = 0; dt < 3; ++dt) oacc[dt] = zero16();
  float m = -1e30f, lsum = 0.f;

  const int krd = qc * 104 + hi * 8;          // K A-frag lane base (within buf)
  const int vrd = 13312 + qc * 72 + hi * 8;   // V A-frag lane base (buf0 base folded in)

#define CVTPK(d, lo_, hi_) asm("v_cvt_pk_bf16_f32 %0, %1, %2" : "=v"(d) : "v"(lo_), "v"(hi_))
#define PLSWAP(x_, y_)     asm("v_permlane32_swap_b32 %0, %1" : "+v"(x_), "+v"(y_))

  for (int kt = 0; kt < 64; ++kt){
    const int cur = kt & 1;
    __syncthreads();
    // issue next tile's global loads early (latency hides under compute)
    if (kt < 63){
      #pragma unroll
      for (int j = 0; j < 3; ++j){ rs[j] = *(const short8*)gp[j]; gp[j] += gstep[j]; }
    }
    const short* Kb = lds + cur * 6656 + krd;
    const short* Vb = lds + cur * 6912 + vrd;

    // ---- QK^T: S^T[k][q], two 32-k subtiles ----
    f32x16 s0 = zero16(), s1 = zero16();
    __builtin_amdgcn_s_setprio(1);
    #pragma unroll
    for (int kw = 0; kw < 6; ++kw){
      short8 kf = *(const short8*)(Kb + kw * 16);
      s0 = MFMA32(kf, qf[kw], s0);
    }
    #pragma unroll
    for (int kw = 0; kw < 6; ++kw){
      short8 kf = *(const short8*)(Kb + 32 * 104 + kw * 16);
      s1 = MFMA32(kf, qf[kw], s1);
    }
    __builtin_amdgcn_s_setprio(0);

    // ---- online softmax: lane-local (one q per lane pair) ----
    float tmax = s0[0];
    #pragma unroll
    for (int r = 1; r < 16; ++r) tmax = fmaxf(tmax, s0[r]);
    #pragma unroll
    for (int r = 0; r < 16; ++r) tmax = fmaxf(tmax, s1[r]);
    tmax = fmaxf(tmax, __shfl_xor(tmax, 32, 64));
    float mnew = fmaxf(m, tmax);
    float alpha = exp2f(m - mnew);
    m = mnew;
    float psum = 0.f;
    #pragma unroll
    for (int r = 0; r < 16; ++r){ float p = exp2f(s0[r] - m); s0[r] = p; psum += p; }
    #pragma unroll
    for (int r = 0; r < 16; ++r){ float p = exp2f(s1[r] - m); s1[r] = p; psum += p; }
    psum += __shfl_xor(psum, 32, 64);
    lsum = lsum * alpha + psum;
    #pragma unroll
    for (int dt = 0; dt < 3; ++dt)
      #pragma unroll
      for (int r = 0; r < 16; ++r) oacc[dt][r] *= alpha;

    // ---- P^T -> bf16 B-frags: 16 cvt_pk + 8 permlane32_swap ----
    short8 pa[4];
    {
      unsigned int a, b;
      union { unsigned int u[4]; short8 s; } pk;
      CVTPK(a, s0[0], s0[1]);  CVTPK(b, s0[4],  s0[5]);  PLSWAP(a, b); pk.u[0] = a; pk.u[2] = b;
      CVTPK(a, s0[2], s0[3]);  CVTPK(b, s0[6],  s0[7]);  PLSWAP(a, b); pk.u[1] = a; pk.u[3] = b;
      pa[0] = pk.s;
      CVTPK(a, s0[8], s0[9]);  CVTPK(b, s0[12], s0[13]); PLSWAP(a, b); pk.u[0] = a; pk.u[2] = b;
      CVTPK(a, s0[10], s0[11]); CVTPK(b, s0[14], s0[15]); PLSWAP(a, b); pk.u[1] = a; pk.u[3] = b;
      pa[1] = pk.s;
      CVTPK(a, s1[0], s1[1]);  CVTPK(b, s1[4],  s1[5]);  PLSWAP(a, b); pk.u[0] = a; pk.u[2] = b;
      CVTPK(a, s1[2], s1[3]);  CVTPK(b, s1[6],  s1[7]);  PLSWAP(a, b); pk.u[1] = a; pk.u[3] = b;
      pa[2] = pk.s;
      CVTPK(a, s1[8], s1[9]);  CVTPK(b, s1[12], s1[13]); PLSWAP(a, b); pk.u[0] = a; pk.u[2] = b;
      CVTPK(a, s1[10], s1[11]); CVTPK(b, s1[14], s1[15]); PLSWAP(a, b); pk.u[1] = a; pk.u[3] = b;
      pa[3] = pk.s;
    }

    // ---- PV: O^T[d][q] += V^T-frag x P-frag ----
    __builtin_amdgcn_s_setprio(1);
    #pragma unroll
    for (int dt = 0; dt < 3; ++dt){
      #pragma unroll
      for (int w = 0; w < 4; ++w){
        short8 vf = *(const short8*)(Vb + dt * 32 * 72 + w * 16);
        oacc[dt] = MFMA32(vf, pa[w], oacc[dt]);
      }
    }
    __builtin_amdgcn_s_setprio(0);

    // ---- stage next tile into the other buffer ----
    if (kt < 63){
      const int nb = cur ^ 1;
      #pragma unroll
      for (int j = 0; j < 3; ++j) *(short8*)(lds + loff[j] + nb * lstep[j]) = rs[j];
    }
  }

  // epilogue: normalize, write bf16 attn output [B][N][C]
  float inv = 1.0f / lsum;
  int b_ = bh >> 3, h = bh & 7;
  unsigned short* orow = ao + (size_t)(b_ * 4096 + q0 + qc) * 768 + h * 96;
  #pragma unroll
  for (int dt = 0; dt < 3; ++dt)
    #pragma unroll
    for (int g = 0; g < 4; ++g){
      short4v sv;
      #pragma unroll
      for (int r = 0; r < 4; ++r) sv[r] = (short)f2b_rne(oacc[dt][g * 4 + r] * inv);
      *(short4v*)(orow + dt * 32 + g * 8 + hi * 4) = sv;
    }
#undef CVTPK
#undef PLSWAP
}

// ---------------- proj GEMM: ao[8192][768] @ wprojt[768][768]^T + bias -> f32 out ----------------
__global__ __launch_bounds__(256) void k_gemm_proj(
    const unsigned short* __restrict__ A,
    const unsigned short* __restrict__ Bt,
    const float* __restrict__ bias,
    float* __restrict__ out)
{
  __shared__ short As[128 * 40];
  __shared__ short Bs[128 * 40];
  int m0 = blockIdx.x * 128, n0 = blockIdx.y * 128;
  int t = threadIdx.x, l = t & 63, w = t >> 6;
  int lr = l & 15, lh = l >> 4;
  int wr = w >> 1, wc = w & 1;

  int row0 = t >> 2, cs0 = t & 3;
  int row1 = row0 + 64;
  const unsigned short* ga0 = A  + (size_t)(m0 + row0) * 768 + cs0 * 8;
  const unsigned short* ga1 = A  + (size_t)(m0 + row1) * 768 + cs0 * 8;
  const unsigned short* gb0 = Bt + (size_t)(n0 + row0) * 768 + cs0 * 8;
  const unsigned short* gb1 = Bt + (size_t)(n0 + row1) * 768 + cs0 * 8;
  short* la0 = As + row0 * 40 + cs0 * 8;
  short* la1 = As + row1 * 40 + cs0 * 8;
  short* lb0 = Bs + row0 * 40 + cs0 * 8;
  short* lb1 = Bs + row1 * 40 + cs0 * 8;

  f32x4 acc[4][4];
  f32x4 z4 = {0.f, 0.f, 0.f, 0.f};
  #pragma unroll
  for (int mf = 0; mf < 4; ++mf)
    #pragma unroll
    for (int nf = 0; nf < 4; ++nf) acc[mf][nf] = z4;

  short8 ra0 = *(const short8*)ga0;
  short8 ra1 = *(const short8*)ga1;
  short8 rb0 = *(const short8*)gb0;
  short8 rb1 = *(const short8*)gb1;

  for (int kt = 0; kt < 24; ++kt){
    __syncthreads();
    *(short8*)la0 = ra0; *(short8*)la1 = ra1;
    *(short8*)lb0 = rb0; *(short8*)lb1 = rb1;
    __syncthreads();
    if (kt < 23){
      ra0 = *(const short8*)(ga0 + (kt + 1) * 32);
      ra1 = *(const short8*)(ga1 + (kt + 1) * 32);
      rb0 = *(const short8*)(gb0 + (kt + 1) * 32);
      rb1 = *(const short8*)(gb1 + (kt + 1) * 32);
    }
    short8 af[4], bfm[4];
    #pragma unroll
    for (int mf = 0; mf < 4; ++mf)
      af[mf] = *(const short8*)(As + (wr * 64 + mf * 16 + lr) * 40 + lh * 8);
    #pragma unroll
    for (int nf = 0; nf < 4; ++nf)
      bfm[nf] = *(const short8*)(Bs + (wc * 64 + nf * 16 + lr) * 40 + lh * 8);
    #pragma unroll
    for (int mf = 0; mf < 4; ++mf)
      #pragma unroll
      for (int nf = 0; nf < 4; ++nf)
        acc[mf][nf] = MFMA16(af[mf], bfm[nf], acc[mf][nf]);
  }

  #pragma unroll
  for (int nf = 0; nf < 4; ++nf){
    int gcol = n0 + wc * 64 + nf * 16 + lr;
    float bb = bias[gcol];
    #pragma unroll
    for (int mf = 0; mf < 4; ++mf){
      int grow = m0 + wr * 64 + mf * 16 + lh * 4;
      #pragma unroll
      for (int r = 0; r < 4; ++r)
        out[(size_t)(grow + r) * 768 + gcol] = acc[mf][nf][r] + bb;
    }
  }
}

extern "C" void kernel_launch(void* const* d_in, const int* in_sizes, int n_in,
                              void* d_out, int out_size, void* d_ws, size_t ws_size,
                              hipStream_t stream) {
  const float* x      = (const float*)d_in[0];
  const float* w_qkv  = (const float*)d_in[1];
  const float* w_proj = (const float*)d_in[2];
  const float* b_proj = (const float*)d_in[3];
  float* out = (float*)d_out;
  char* ws = (char*)d_ws;

  // workspace layout (all 16B-aligned); ao aliases xb (xb dead after qkv gemm)
  unsigned short* xb     = (unsigned short*)(ws);                 // 12,582,912 B
  unsigned short* wqkvt  = (unsigned short*)(ws + 12582912);      //  3,538,944 B
  unsigned short* wprojt = (unsigned short*)(ws + 16121856);      //  1,179,648 B
  unsigned short* qbuf   = (unsigned short*)(ws + 17301504);      // 12,582,912 B
  unsigned short* kbuf   = (unsigned short*)(ws + 29884416);      // 12,582,912 B
  unsigned short* vtb    = (unsigned short*)(ws + 42467328);      // 12,582,912 B
  unsigned short* aob    = xb;                                    // reuse

  k_cvt<<<3072, 256, 0, stream>>>(x, xb, 786432);                       // 2*4096*768 / 8
  k_transpose_cvt<<<dim3(72, 24), dim3(32, 8), 0, stream>>>(w_qkv, wqkvt, 768, 2304);
  k_transpose_cvt<<<dim3(24, 24), dim3(32, 8), 0, stream>>>(w_proj, wprojt, 768, 768);
  k_gemm_qkv<<<dim3(64, 18), 256, 0, stream>>>(xb, wqkvt, qbuf, kbuf, vtb);
  k_attn2<<<dim3(16, 16), 512, 0, stream>>>(qbuf, kbuf, vtb, aob);
  k_gemm_proj<<<dim3(64, 6), 256, 0, stream>>>(aob, wprojt, b_proj, out);
}